// Round 1
// baseline (2454.990 us; speedup 1.0000x reference)
//
#include <hip/hip_runtime.h>
#include <stdint.h>

#define NN 50000
#define DEG 16
#define MT 64
#define NBLK ((NN + MT - 1) / MT)

typedef short bf16x8 __attribute__((ext_vector_type(8)));
typedef float f32x4 __attribute__((ext_vector_type(4)));
typedef unsigned short u16;
typedef unsigned int u32;

static __device__ __forceinline__ u16 f2bf(float f) {
  union { float f; u32 u; } v; v.f = f;
  u32 u = v.u + 0x7FFFu + ((v.u >> 16) & 1u);   // round-to-nearest-even
  return (u16)(u >> 16);
}
static __device__ __forceinline__ float sigm(float x) {
  return 1.f / (1.f + __expf(-x));
}
static __device__ __forceinline__ float tanhf_(float x) {
  float e = __expf(2.f * x);
  return 1.f - 2.f / (e + 1.f);
}

// ---------------------------------------------------------------------------
// Combined prep kernel: bf16-convert x, prepack MFMA B-fragments, bias sums.
// B-fragment order for wave w, ntile nt, ktile kt, lane l, elem j:
//   offset = (((w*NT + nt)*KT + kt)*64 + l)*8 + j
//   value  = W[n][k],  n = col-owner of lane (l&15),  k = kt*32 + (l>>4)*8 + j
// ---------------------------------------------------------------------------
__global__ void k_prep(const float* __restrict__ x, u16* __restrict__ xb,
                       const float* __restrict__ wih1, const float* __restrict__ whh1, u16* __restrict__ wpk1,
                       const float* __restrict__ wih2, const float* __restrict__ whh2, u16* __restrict__ wpk2,
                       const float* __restrict__ lr1, const float* __restrict__ ll1, u16* __restrict__ epk1,
                       const float* __restrict__ lr2, const float* __restrict__ ll2, u16* __restrict__ epk2,
                       const float* __restrict__ linw, u16* __restrict__ hpk,
                       const float* __restrict__ bi1, const float* __restrict__ bh1, float* __restrict__ bs1,
                       const float* __restrict__ bi2, const float* __restrict__ bh2, float* __restrict__ bs2) {
  int b = blockIdx.x;
  if (b < 128) {
    // gate weights: W = [w_ih ; w_hh] along K (256), gate-ordered cols.
    const float* wih = (b < 64) ? wih1 : wih2;
    const float* whh = (b < 64) ? whh1 : whh2;
    u16* wpk = (b < 64) ? wpk1 : wpk2;
    int t = (b & 63) * 256 + threadIdx.x;          // 0..16383
    int lane = t & 63, kt = (t >> 6) & 7, nt = (t >> 9) & 7, w = (t >> 12) & 3;
    int n = (nt >> 1) * 128 + w * 32 + (nt & 1) * 16 + (lane & 15);
    int k0 = kt * 32 + (lane >> 4) * 8;
#pragma unroll
    for (int j = 0; j < 8; ++j) {
      int k = k0 + j;
      wpk[t * 8 + j] = f2bf(k < 128 ? wih[n * 128 + k] : whh[n * 128 + k - 128]);
    }
  } else if (b < 160) {
    // epilogue weights: out = lin_r(x) [k<128] + lin_l(h) [k>=128]
    const float* lrw = (b < 144) ? lr1 : lr2;
    const float* llw = (b < 144) ? ll1 : ll2;
    u16* epk = (b < 144) ? epk1 : epk2;
    int t = ((b - 128) & 15) * 256 + threadIdx.x;  // 0..4095
    int lane = t & 63, kt = (t >> 6) & 7, nt = (t >> 9) & 1, w = (t >> 10) & 3;
    int n = w * 32 + nt * 16 + (lane & 15);
    int k0 = kt * 32 + (lane >> 4) * 8;
#pragma unroll
    for (int j = 0; j < 8; ++j) {
      int k = k0 + j;
      epk[t * 8 + j] = f2bf(k < 128 ? lrw[n * 128 + k] : llw[n * 128 + k - 128]);
    }
  } else if (b < 164) {
    // head weights [64,128]
    int t = (b - 160) * 256 + threadIdx.x;         // 0..1023
    int lane = t & 63, kt = (t >> 6) & 3, w = (t >> 8) & 3;
    int n = w * 16 + (lane & 15);
    int k0 = kt * 32 + (lane >> 4) * 8;
#pragma unroll
    for (int j = 0; j < 8; ++j) hpk[t * 8 + j] = f2bf(linw[n * 128 + k0 + j]);
  } else if (b < 168) {
    int t = (b - 164) * 256 + threadIdx.x;         // 0..1023
    if (t < 512) bs1[t] = bi1[t] + bh1[t];
    else bs2[t - 512] = bi2[t - 512] + bh2[t - 512];
  } else {
    // convert x -> bf16, vectorized
    int i = (b - 168) * 256 + threadIdx.x;
    int stride = (gridDim.x - 168) * 256;
    for (; i < NN * 128 / 4; i += stride) {
      float4 v = ((const float4*)x)[i];
      ushort4 o;
      o.x = f2bf(v.x); o.y = f2bf(v.y); o.z = f2bf(v.z); o.w = f2bf(v.w);
      ((ushort4*)xb)[i] = o;
    }
  }
}

// ---------------------------------------------------------------------------
// Fused SAGE-LSTM layer. Block = 64 nodes, 4 waves; wave w owns hidden
// units [32w,32w+32) (its i/f/g/o gate rows), so c/h updates are wave-local.
// LDS: AX[2] double-buffered neighbor-feature tiles, AH recurrent h tile,
// all XOR-swizzled (byte ^= (row&7)<<4) to kill the 256B-stride bank conflict.
// ---------------------------------------------------------------------------
template <int L2>
__global__ __launch_bounds__(256, 2) void k_layer(
    const u16* __restrict__ xin, const int* __restrict__ src,
    const u16* __restrict__ wpk, const float* __restrict__ bsum,
    const u16* __restrict__ epk, const float* __restrict__ linlb,
    u16* __restrict__ hout, const u16* __restrict__ hpk,
    const float* __restrict__ linb, float* __restrict__ dout) {
  __shared__ u16 AX[2][MT * 128];
  __shared__ u16 AH[MT * 128];
  __shared__ int IDX[MT * DEG];

  const int tid = threadIdx.x;
  const int w = tid >> 6, l = tid & 63;
  const int lr = l & 15, lh = l >> 4;
  const int node0 = blockIdx.x * MT;

  // stage neighbor indices (IDX[m][d]); contiguous in src
#pragma unroll
  for (int q = 0; q < 4; ++q) {
    int t = tid + q * 256;
    IDX[t] = (node0 + (t >> 4) < NN) ? src[node0 * DEG + t] : 0;
  }
  // gate biases (b_ih+b_hh) for this lane's gate columns
  float gb[8];
#pragma unroll
  for (int nt = 0; nt < 8; ++nt)
    gb[nt] = bsum[(nt >> 1) * 128 + w * 32 + (nt & 1) * 16 + lr];
  float eb0 = linlb[w * 32 + lr], eb1 = linlb[w * 32 + 16 + lr];
  __syncthreads();

  // stage x_0 (wave w owns rows [16w,16w+16))
  uint4 xst[4];
#pragma unroll
  for (int q = 0; q < 4; ++q) {
    int row = w * 16 + q * 4 + lh;
    xst[q] = *(const uint4*)(xin + (size_t)IDX[row * DEG] * 128 + lr * 8);
  }
#pragma unroll
  for (int q = 0; q < 4; ++q) {
    int row = w * 16 + q * 4 + lh;
    *(uint4*)((char*)AX[0] + row * 256 + ((lr * 16) ^ ((row & 7) << 4))) = xst[q];
  }

  f32x4 c[4][2];
#pragma unroll
  for (int mt = 0; mt < 4; ++mt) {
    c[mt][0] = (f32x4){0.f, 0.f, 0.f, 0.f};
    c[mt][1] = (f32x4){0.f, 0.f, 0.f, 0.f};
  }
  __syncthreads();

  const u16* wpkw = wpk + (size_t)w * 32768;  // wave's 8x8 fragment panel

#pragma unroll 1
  for (int step = 0; step < DEG; ++step) {
    // prefetch next x-tile rows into regs (last step: node's own features)
#pragma unroll
    for (int q = 0; q < 4; ++q) {
      int row = w * 16 + q * 4 + lh;
      int idx = (step < DEG - 1) ? IDX[row * DEG + step + 1]
                                 : ((node0 + row < NN) ? node0 + row : NN - 1);
      xst[q] = *(const uint4*)(xin + (size_t)idx * 128 + lr * 8);
    }

    const u16* axc = AX[step & 1];
    f32x4 acc[4][8];
#pragma unroll
    for (int mt = 0; mt < 4; ++mt)
#pragma unroll
      for (int nt = 0; nt < 8; ++nt) acc[mt][nt] = (f32x4){0.f, 0.f, 0.f, 0.f};

    // x-part of gates (K tiles 0..3)
#pragma unroll
    for (int kt = 0; kt < 4; ++kt) {
      bf16x8 af[4];
#pragma unroll
      for (int mt = 0; mt < 4; ++mt) {
        int row = mt * 16 + lr;
        af[mt] = *(const bf16x8*)((const char*)axc + row * 256 +
                                  ((kt * 64 + lh * 16) ^ ((row & 7) << 4)));
      }
#pragma unroll
      for (int nt = 0; nt < 8; ++nt) {
        bf16x8 bf = *(const bf16x8*)(wpkw + ((nt * 8 + kt) * 64 + l) * 8);
#pragma unroll
        for (int mt = 0; mt < 4; ++mt)
          acc[mt][nt] = __builtin_amdgcn_mfma_f32_16x16x32_bf16(af[mt], bf, acc[mt][nt], 0, 0, 0);
      }
    }
    // h-part of gates (K tiles 4..7); h==0 at step 0
    if (step) {
#pragma unroll
      for (int kt = 0; kt < 4; ++kt) {
        bf16x8 af[4];
#pragma unroll
        for (int mt = 0; mt < 4; ++mt) {
          int row = mt * 16 + lr;
          af[mt] = *(const bf16x8*)((const char*)AH + row * 256 +
                                    ((kt * 64 + lh * 16) ^ ((row & 7) << 4)));
        }
#pragma unroll
        for (int nt = 0; nt < 8; ++nt) {
          bf16x8 bf = *(const bf16x8*)(wpkw + ((nt * 8 + 4 + kt) * 64 + l) * 8);
#pragma unroll
          for (int mt = 0; mt < 4; ++mt)
            acc[mt][nt] = __builtin_amdgcn_mfma_f32_16x16x32_bf16(af[mt], bf, acc[mt][nt], 0, 0, 0);
        }
      }
    }

    __syncthreads();  // all waves done reading AX[cur]/AH

    // LSTM elementwise update; write new h (bf16) into AH, wave-local cols
#pragma unroll
    for (int mt = 0; mt < 4; ++mt)
#pragma unroll
      for (int h2 = 0; h2 < 2; ++h2)
#pragma unroll
        for (int r = 0; r < 4; ++r) {
          float iv = sigm(acc[mt][h2][r] + gb[h2]);
          float fv = sigm(acc[mt][2 + h2][r] + gb[2 + h2]);
          float gv = tanhf_(acc[mt][4 + h2][r] + gb[4 + h2]);
          float ov = sigm(acc[mt][6 + h2][r] + gb[6 + h2]);
          float cv = fv * c[mt][h2][r] + iv * gv;
          c[mt][h2][r] = cv;
          int row = mt * 16 + lh * 4 + r;
          int jj = 2 * (w * 32 + h2 * 16 + lr);
          *(u16*)((char*)AH + row * 256 + (jj ^ ((row & 7) << 4))) =
              f2bf(ov * tanhf_(cv));
        }

    // commit prefetched x-tile into the other buffer
#pragma unroll
    for (int q = 0; q < 4; ++q) {
      int row = w * 16 + q * 4 + lh;
      *(uint4*)((char*)AX[(step + 1) & 1] + row * 256 +
                ((lr * 16) ^ ((row & 7) << 4))) = xst[q];
    }
    __syncthreads();
  }

  // Epilogue: out = lin_r(x_own) + lin_l(h_final) + b, ReLU.
  // AX[0] now holds the node's own input row (DEG even), AH the final h.
  f32x4 eacc[4][2];
#pragma unroll
  for (int mt = 0; mt < 4; ++mt) {
    eacc[mt][0] = (f32x4){0.f, 0.f, 0.f, 0.f};
    eacc[mt][1] = (f32x4){0.f, 0.f, 0.f, 0.f};
  }
#pragma unroll
  for (int kt = 0; kt < 8; ++kt) {
    const u16* srcb = (kt < 4) ? AX[0] : AH;
    int kb0 = (kt & 3) * 64 + lh * 16;
    bf16x8 af[4];
#pragma unroll
    for (int mt = 0; mt < 4; ++mt) {
      int row = mt * 16 + lr;
      af[mt] = *(const bf16x8*)((const char*)srcb + row * 256 + (kb0 ^ ((row & 7) << 4)));
    }
#pragma unroll
    for (int nt = 0; nt < 2; ++nt) {
      bf16x8 bf = *(const bf16x8*)(epk + (((w * 2 + nt) * 8 + kt) * 64 + l) * 8);
#pragma unroll
      for (int mt = 0; mt < 4; ++mt)
        eacc[mt][nt] = __builtin_amdgcn_mfma_f32_16x16x32_bf16(af[mt], bf, eacc[mt][nt], 0, 0, 0);
    }
  }

  if constexpr (!L2) {
#pragma unroll
    for (int mt = 0; mt < 4; ++mt)
#pragma unroll
      for (int nt = 0; nt < 2; ++nt)
#pragma unroll
        for (int r = 0; r < 4; ++r) {
          int node = node0 + mt * 16 + lh * 4 + r;
          if (node < NN) {
            float v = fmaxf(eacc[mt][nt][r] + (nt ? eb1 : eb0), 0.f);
            hout[(size_t)node * 128 + w * 32 + nt * 16 + lr] = f2bf(v);
          }
        }
  } else {
    // stash relu(h2) in AX[1], then fused 128->64 head
#pragma unroll
    for (int mt = 0; mt < 4; ++mt)
#pragma unroll
      for (int nt = 0; nt < 2; ++nt)
#pragma unroll
        for (int r = 0; r < 4; ++r) {
          int row = mt * 16 + lh * 4 + r;
          float v = fmaxf(eacc[mt][nt][r] + (nt ? eb1 : eb0), 0.f);
          int jj = 2 * (w * 32 + nt * 16 + lr);
          *(u16*)((char*)AX[1] + row * 256 + (jj ^ ((row & 7) << 4))) = f2bf(v);
        }
    __syncthreads();
    f32x4 hacc[4];
#pragma unroll
    for (int mt = 0; mt < 4; ++mt) hacc[mt] = (f32x4){0.f, 0.f, 0.f, 0.f};
#pragma unroll
    for (int kt = 0; kt < 4; ++kt) {
      bf16x8 af[4];
#pragma unroll
      for (int mt = 0; mt < 4; ++mt) {
        int row = mt * 16 + lr;
        af[mt] = *(const bf16x8*)((const char*)AX[1] + row * 256 +
                                  ((kt * 64 + lh * 16) ^ ((row & 7) << 4)));
      }
      bf16x8 bf = *(const bf16x8*)(hpk + ((w * 4 + kt) * 64 + l) * 8);
#pragma unroll
      for (int mt = 0; mt < 4; ++mt)
        hacc[mt] = __builtin_amdgcn_mfma_f32_16x16x32_bf16(af[mt], bf, hacc[mt], 0, 0, 0);
    }
    float hb0 = linb[w * 16 + lr];
#pragma unroll
    for (int mt = 0; mt < 4; ++mt)
#pragma unroll
      for (int r = 0; r < 4; ++r) {
        int node = node0 + mt * 16 + lh * 4 + r;
        if (node < NN) dout[(size_t)node * 64 + w * 16 + lr] = hacc[mt][r] + hb0;
      }
  }
}

extern "C" void kernel_launch(void* const* d_in, const int* in_sizes, int n_in,
                              void* d_out, int out_size, void* d_ws, size_t ws_size,
                              hipStream_t stream) {
  const float* x    = (const float*)d_in[0];
  const int*   edge = (const int*)d_in[1];   // src = first N*DEG entries
  const float* wih1 = (const float*)d_in[2];
  const float* whh1 = (const float*)d_in[3];
  const float* bih1 = (const float*)d_in[4];
  const float* bhh1 = (const float*)d_in[5];
  const float* ll1w = (const float*)d_in[6];
  const float* ll1b = (const float*)d_in[7];
  const float* lr1w = (const float*)d_in[8];
  const float* wih2 = (const float*)d_in[9];
  const float* whh2 = (const float*)d_in[10];
  const float* bih2 = (const float*)d_in[11];
  const float* bhh2 = (const float*)d_in[12];
  const float* ll2w = (const float*)d_in[13];
  const float* ll2b = (const float*)d_in[14];
  const float* lr2w = (const float*)d_in[15];
  const float* linw = (const float*)d_in[16];
  const float* linb = (const float*)d_in[17];

  char* ws = (char*)d_ws;
  u16* xb    = (u16*)(ws);                       // 12,800,000 B
  u16* h1b   = (u16*)(ws + 12800000);            // 12,800,000 B
  u16* wpk1  = (u16*)(ws + 25600000);            //    262,144 B
  u16* wpk2  = (u16*)(ws + 25862144);            //    262,144 B
  u16* epk1  = (u16*)(ws + 26124288);            //     65,536 B
  u16* epk2  = (u16*)(ws + 26189824);            //     65,536 B
  u16* hpk   = (u16*)(ws + 26255360);            //     16,384 B
  float* bs1 = (float*)(ws + 26271744);          //      2,048 B
  float* bs2 = (float*)(ws + 26273792);          //      2,048 B

  k_prep<<<1000, 256, 0, stream>>>(x, xb,
                                   wih1, whh1, wpk1, wih2, whh2, wpk2,
                                   lr1w, ll1w, epk1, lr2w, ll2w, epk2,
                                   linw, hpk,
                                   bih1, bhh1, bs1, bih2, bhh2, bs2);
  k_layer<0><<<NBLK, 256, 0, stream>>>(xb, edge, wpk1, bs1, epk1, ll1b,
                                       h1b, nullptr, nullptr, nullptr);
  k_layer<1><<<NBLK, 256, 0, stream>>>(h1b, edge, wpk2, bs2, epk2, ll2b,
                                       nullptr, hpk, linb, (float*)d_out);
}

// Round 2
// 1593.099 us; speedup vs baseline: 1.5410x; 1.5410x over previous
//
#include <hip/hip_runtime.h>
#include <stdint.h>

#define NN 50000
#define DEG 16
#define MT 64
#define NBLK ((NN + MT - 1) / MT)

typedef short bf16x8 __attribute__((ext_vector_type(8)));
typedef float f32x4 __attribute__((ext_vector_type(4)));
typedef unsigned short u16;
typedef unsigned int u32;

static __device__ __forceinline__ u16 f2bf(float f) {
  union { float f; u32 u; } v; v.f = f;
  u32 u = v.u + 0x7FFFu + ((v.u >> 16) & 1u);   // round-to-nearest-even
  return (u16)(u >> 16);
}
static __device__ __forceinline__ float sigm(float x) {
  return 1.f / (1.f + __expf(-x));
}
static __device__ __forceinline__ float tanhf_(float x) {
  float e = __expf(2.f * x);
  return 1.f - 2.f / (e + 1.f);
}
static __device__ __forceinline__ void gload_lds16(const void* g, void* l) {
  __builtin_amdgcn_global_load_lds(
      (const __attribute__((address_space(1))) void*)g,
      (__attribute__((address_space(3))) void*)l, 16, 0, 0);
}

// ---------------------------------------------------------------------------
// Prep: bf16-convert x, prepack MFMA B-fragments (8-wave layout), bias sums.
// Gate-weight frag (w<8, nt=gate<4, kt<8, lane, j):
//   wpk[(((w*4+nt)*8+kt)*64+lane)*8+j] = W[col][k],
//   col = nt*128 + w*16 + (lane&15),  k = kt*32 + (lane>>4)*8 + j,
//   W = [w_ih | w_hh] along K.
// ---------------------------------------------------------------------------
__global__ void k_prep(const float* __restrict__ x, u16* __restrict__ xb,
                       const float* __restrict__ wih1, const float* __restrict__ whh1, u16* __restrict__ wpk1,
                       const float* __restrict__ wih2, const float* __restrict__ whh2, u16* __restrict__ wpk2,
                       const float* __restrict__ lr1, const float* __restrict__ ll1, u16* __restrict__ epk1,
                       const float* __restrict__ lr2, const float* __restrict__ ll2, u16* __restrict__ epk2,
                       const float* __restrict__ linw, u16* __restrict__ hpk,
                       const float* __restrict__ bi1, const float* __restrict__ bh1, float* __restrict__ bs1,
                       const float* __restrict__ bi2, const float* __restrict__ bh2, float* __restrict__ bs2) {
  int b = blockIdx.x;
  if (b < 128) {
    const float* wih = (b < 64) ? wih1 : wih2;
    const float* whh = (b < 64) ? whh1 : whh2;
    u16* wpk = (b < 64) ? wpk1 : wpk2;
    int t = (b & 63) * 256 + threadIdx.x;          // 0..16383
    int lane = t & 63, kt = (t >> 6) & 7, nt = (t >> 9) & 3, w = (t >> 11) & 7;
    int col = nt * 128 + w * 16 + (lane & 15);
    int k0 = kt * 32 + (lane >> 4) * 8;
#pragma unroll
    for (int j = 0; j < 8; ++j) {
      int k = k0 + j;
      wpk[t * 8 + j] = f2bf(k < 128 ? wih[col * 128 + k] : whh[col * 128 + k - 128]);
    }
  } else if (b < 160) {
    // epilogue weights: k<128 lin_r (over x), k>=128 lin_l (over h)
    const float* lrw = (b < 144) ? lr1 : lr2;
    const float* llw = (b < 144) ? ll1 : ll2;
    u16* epk = (b < 144) ? epk1 : epk2;
    int t = ((b - 128) & 15) * 256 + threadIdx.x;  // 0..4095
    int lane = t & 63, kt = (t >> 6) & 7, w = (t >> 9) & 7;
    int col = w * 16 + (lane & 15);
    int k0 = kt * 32 + (lane >> 4) * 8;
#pragma unroll
    for (int j = 0; j < 8; ++j) {
      int k = k0 + j;
      epk[t * 8 + j] = f2bf(k < 128 ? lrw[col * 128 + k] : llw[col * 128 + k - 128]);
    }
  } else if (b < 164) {
    // head weights [64,128], waves 0..3
    int t = (b - 160) * 256 + threadIdx.x;         // 0..1023
    int lane = t & 63, kt = (t >> 6) & 3, w = (t >> 8) & 3;
    int col = w * 16 + (lane & 15);
    int k0 = kt * 32 + (lane >> 4) * 8;
#pragma unroll
    for (int j = 0; j < 8; ++j) hpk[t * 8 + j] = f2bf(linw[col * 128 + k0 + j]);
  } else if (b < 168) {
    int t = (b - 164) * 256 + threadIdx.x;         // 0..1023
    if (t < 512) bs1[t] = bi1[t] + bh1[t];
    else if (t < 1024) bs2[t - 512] = bi2[t - 512] + bh2[t - 512];
  } else {
    int i = (b - 168) * 256 + threadIdx.x;
    int stride = (gridDim.x - 168) * 256;
    for (; i < NN * 128 / 4; i += stride) {
      float4 v = ((const float4*)x)[i];
      ushort4 o;
      o.x = f2bf(v.x); o.y = f2bf(v.y); o.z = f2bf(v.z); o.w = f2bf(v.w);
      ((ushort4*)xb)[i] = o;
    }
  }
}

// ---------------------------------------------------------------------------
// Fused SAGE-LSTM layer, v2: 512 threads = 8 waves, MT=64 nodes.
// Wave w owns hidden units [16w,16w+16): acc[4 mt][4 gates] = 64 VGPR.
// Gather next-step x directly into LDS via global_load_lds (linear dest,
// pre-swizzled global source). AH double-buffered -> ONE barrier per step.
// All LDS tiles XOR-swizzled: byte ^= (row&15)<<4.
// ---------------------------------------------------------------------------
template <int L2>
__global__ __launch_bounds__(512, 4) void k_layer(
    const u16* __restrict__ xin, const int* __restrict__ src,
    const u16* __restrict__ wpk, const float* __restrict__ bsum,
    const u16* __restrict__ epk, const float* __restrict__ linlb,
    u16* __restrict__ hout, const u16* __restrict__ hpk,
    const float* __restrict__ linb, float* __restrict__ dout) {
  __shared__ __align__(16) u16 AX[2][MT * 128];   // 2 x 16 KB
  __shared__ __align__(16) u16 AH[2][MT * 128];   // 2 x 16 KB
  __shared__ int IDX[MT * DEG];                   // 4 KB

  const int tid = threadIdx.x;
  const int w = tid >> 6, l = tid & 63;
  const int lr = l & 15, lh = l >> 4;
  const int node0 = blockIdx.x * MT;

  // neighbor indices (IDX[node][d]), contiguous in src
#pragma unroll
  for (int q = 0; q < 2; ++q) {
    int t = tid + q * 512;
    IDX[t] = (node0 + (t >> 4) < NN) ? src[node0 * DEG + t] : 0;
  }
  float gb[4];
#pragma unroll
  for (int g = 0; g < 4; ++g) gb[g] = bsum[g * 128 + w * 16 + lr];
  float eb = linlb[w * 16 + lr];
  __syncthreads();  // IDX ready

  // gather x_0 into AX[0]; wave w stages rows [8w, 8w+8) in 2 passes
#pragma unroll
  for (int p = 0; p < 2; ++p) {
    int row = w * 8 + p * 4 + lh;
    int idx = IDX[row * DEG];
    const char* gsw = (const char*)(xin + (size_t)idx * 128) +
                      ((lr * 16) ^ ((row & 15) << 4));
    gload_lds16(gsw, &AX[0][(w * 8 + p * 4) * 128]);
  }

  f32x4 c[4];
#pragma unroll
  for (int mt = 0; mt < 4; ++mt) c[mt] = (f32x4){0.f, 0.f, 0.f, 0.f};
  __syncthreads();  // x_0 gathered (vmcnt drained by syncthreads)

#pragma unroll 1
  for (int step = 0; step < DEG; ++step) {
    const int cb = step & 1, nb = cb ^ 1;
    const u16* axc = AX[cb];
    const u16* ahc = AH[cb];

    f32x4 acc[4][4];
#pragma unroll
    for (int mt = 0; mt < 4; ++mt)
#pragma unroll
      for (int g = 0; g < 4; ++g) acc[mt][g] = (f32x4){0.f, 0.f, 0.f, 0.f};

    // x-part of gates: K tiles 0..3
#pragma unroll
    for (int kt = 0; kt < 4; ++kt) {
      bf16x8 af[4];
#pragma unroll
      for (int mt = 0; mt < 4; ++mt) {
        int row = mt * 16 + lr;
        af[mt] = *(const bf16x8*)((const char*)axc + row * 256 +
                                  ((kt * 64 + lh * 16) ^ ((row & 15) << 4)));
      }
#pragma unroll
      for (int g = 0; g < 4; ++g) {
        bf16x8 bf = *(const bf16x8*)(wpk + (size_t)(((w * 4 + g) * 8 + kt) * 64 + l) * 8);
#pragma unroll
        for (int mt = 0; mt < 4; ++mt)
          acc[mt][g] = __builtin_amdgcn_mfma_f32_16x16x32_bf16(af[mt], bf, acc[mt][g], 0, 0, 0);
      }
    }
    // h-part of gates: K tiles 4..7 (h == 0 at step 0)
    if (step) {
#pragma unroll
      for (int kt = 0; kt < 4; ++kt) {
        bf16x8 af[4];
#pragma unroll
        for (int mt = 0; mt < 4; ++mt) {
          int row = mt * 16 + lr;
          af[mt] = *(const bf16x8*)((const char*)ahc + row * 256 +
                                    ((kt * 64 + lh * 16) ^ ((row & 15) << 4)));
        }
#pragma unroll
        for (int g = 0; g < 4; ++g) {
          bf16x8 bf = *(const bf16x8*)(wpk + (size_t)(((w * 4 + g) * 8 + 4 + kt) * 64 + l) * 8);
#pragma unroll
          for (int mt = 0; mt < 4; ++mt)
            acc[mt][g] = __builtin_amdgcn_mfma_f32_16x16x32_bf16(af[mt], bf, acc[mt][g], 0, 0, 0);
        }
      }
    }

    // issue next-step gather into AX[nb] AFTER all B loads (vmcnt ordering);
    // latency hides under the elementwise phase, drained at the barrier.
#pragma unroll
    for (int p = 0; p < 2; ++p) {
      int row = w * 8 + p * 4 + lh;
      int idx = (step < DEG - 1) ? IDX[row * DEG + step + 1]
                                 : ((node0 + row < NN) ? node0 + row : NN - 1);
      const char* gsw = (const char*)(xin + (size_t)idx * 128) +
                        ((lr * 16) ^ ((row & 15) << 4));
      gload_lds16(gsw, &AX[nb][(w * 8 + p * 4) * 128]);
    }

    // LSTM elementwise update; write new h (bf16) into AH[nb]
#pragma unroll
    for (int mt = 0; mt < 4; ++mt)
#pragma unroll
      for (int r = 0; r < 4; ++r) {
        float iv = sigm(acc[mt][0][r] + gb[0]);
        float fv = sigm(acc[mt][1][r] + gb[1]);
        float gv = tanhf_(acc[mt][2][r] + gb[2]);
        float ov = sigm(acc[mt][3][r] + gb[3]);
        float cv = fv * c[mt][r] + iv * gv;
        c[mt][r] = cv;
        int row = mt * 16 + lh * 4 + r;
        int jj = 2 * (w * 16 + lr);
        *(u16*)((char*)AH[nb] + row * 256 + (jj ^ ((row & 15) << 4))) =
            f2bf(ov * tanhf_(cv));
      }
    __syncthreads();
  }

  // Epilogue: out = lin_r(x_own) + lin_l(h_final) + b, ReLU.
  // AX[0] holds own input row (written at step 15), AH[0] the final h.
  f32x4 eacc[4];
#pragma unroll
  for (int mt = 0; mt < 4; ++mt) eacc[mt] = (f32x4){0.f, 0.f, 0.f, 0.f};
#pragma unroll
  for (int kt = 0; kt < 8; ++kt) {
    const u16* srcb = (kt < 4) ? AX[0] : AH[0];
    int kb = (kt & 3) * 64 + lh * 16;
    bf16x8 af[4];
#pragma unroll
    for (int mt = 0; mt < 4; ++mt) {
      int row = mt * 16 + lr;
      af[mt] = *(const bf16x8*)((const char*)srcb + row * 256 +
                                (kb ^ ((row & 15) << 4)));
    }
    bf16x8 bf = *(const bf16x8*)(epk + (size_t)((w * 8 + kt) * 64 + l) * 8);
#pragma unroll
    for (int mt = 0; mt < 4; ++mt)
      eacc[mt] = __builtin_amdgcn_mfma_f32_16x16x32_bf16(af[mt], bf, eacc[mt], 0, 0, 0);
  }

  if constexpr (!L2) {
#pragma unroll
    for (int mt = 0; mt < 4; ++mt)
#pragma unroll
      for (int r = 0; r < 4; ++r) {
        int node = node0 + mt * 16 + lh * 4 + r;
        if (node < NN) {
          float v = fmaxf(eacc[mt][r] + eb, 0.f);
          hout[(size_t)node * 128 + w * 16 + lr] = f2bf(v);
        }
      }
  } else {
    // stash relu(h2) into AX[1], then fused 128->64 head (waves 0..3)
#pragma unroll
    for (int mt = 0; mt < 4; ++mt)
#pragma unroll
      for (int r = 0; r < 4; ++r) {
        int row = mt * 16 + lh * 4 + r;
        float v = fmaxf(eacc[mt][r] + eb, 0.f);
        int jj = 2 * (w * 16 + lr);
        *(u16*)((char*)AX[1] + row * 256 + (jj ^ ((row & 15) << 4))) = f2bf(v);
      }
    __syncthreads();
    if (w < 4) {
      f32x4 hacc[4];
#pragma unroll
      for (int mt = 0; mt < 4; ++mt) hacc[mt] = (f32x4){0.f, 0.f, 0.f, 0.f};
#pragma unroll
      for (int kt = 0; kt < 4; ++kt) {
        bf16x8 af[4];
#pragma unroll
        for (int mt = 0; mt < 4; ++mt) {
          int row = mt * 16 + lr;
          af[mt] = *(const bf16x8*)((const char*)AX[1] + row * 256 +
                                    ((kt * 64 + lh * 16) ^ ((row & 15) << 4)));
        }
        bf16x8 bf = *(const bf16x8*)(hpk + (size_t)((w * 4 + kt) * 64 + l) * 8);
#pragma unroll
        for (int mt = 0; mt < 4; ++mt)
          hacc[mt] = __builtin_amdgcn_mfma_f32_16x16x32_bf16(af[mt], bf, hacc[mt], 0, 0, 0);
      }
      float hb = linb[w * 16 + lr];
#pragma unroll
      for (int mt = 0; mt < 4; ++mt)
#pragma unroll
        for (int r = 0; r < 4; ++r) {
          int node = node0 + mt * 16 + lh * 4 + r;
          if (node < NN) dout[(size_t)node * 64 + w * 16 + lr] = hacc[mt][r] + hb;
        }
    }
  }
}

extern "C" void kernel_launch(void* const* d_in, const int* in_sizes, int n_in,
                              void* d_out, int out_size, void* d_ws, size_t ws_size,
                              hipStream_t stream) {
  const float* x    = (const float*)d_in[0];
  const int*   edge = (const int*)d_in[1];   // src = first N*DEG entries
  const float* wih1 = (const float*)d_in[2];
  const float* whh1 = (const float*)d_in[3];
  const float* bih1 = (const float*)d_in[4];
  const float* bhh1 = (const float*)d_in[5];
  const float* ll1w = (const float*)d_in[6];
  const float* ll1b = (const float*)d_in[7];
  const float* lr1w = (const float*)d_in[8];
  const float* wih2 = (const float*)d_in[9];
  const float* whh2 = (const float*)d_in[10];
  const float* bih2 = (const float*)d_in[11];
  const float* bhh2 = (const float*)d_in[12];
  const float* ll2w = (const float*)d_in[13];
  const float* ll2b = (const float*)d_in[14];
  const float* lr2w = (const float*)d_in[15];
  const float* linw = (const float*)d_in[16];
  const float* linb = (const float*)d_in[17];

  char* ws = (char*)d_ws;
  u16* xb    = (u16*)(ws);                       // 12,800,000 B
  u16* h1b   = (u16*)(ws + 12800000);            // 12,800,000 B
  u16* wpk1  = (u16*)(ws + 25600000);            //    262,144 B
  u16* wpk2  = (u16*)(ws + 25862144);            //    262,144 B
  u16* epk1  = (u16*)(ws + 26124288);            //     65,536 B
  u16* epk2  = (u16*)(ws + 26189824);            //     65,536 B
  u16* hpk   = (u16*)(ws + 26255360);            //     16,384 B
  float* bs1 = (float*)(ws + 26271744);          //      2,048 B
  float* bs2 = (float*)(ws + 26273792);          //      2,048 B

  k_prep<<<1000, 256, 0, stream>>>(x, xb,
                                   wih1, whh1, wpk1, wih2, whh2, wpk2,
                                   lr1w, ll1w, epk1, lr2w, ll2w, epk2,
                                   linw, hpk,
                                   bih1, bhh1, bs1, bih2, bhh2, bs2);
  k_layer<0><<<NBLK, 512, 0, stream>>>(xb, edge, wpk1, bs1, epk1, ll1b,
                                       h1b, nullptr, nullptr, nullptr);
  k_layer<1><<<NBLK, 512, 0, stream>>>(h1b, edge, wpk2, bs2, epk2, ll2b,
                                       nullptr, hpk, linb, (float*)d_out);
}

// Round 3
// 1035.191 us; speedup vs baseline: 2.3715x; 1.5389x over previous
//
#include <hip/hip_runtime.h>
#include <stdint.h>

#define NN 50000
#define DEG 16
#define MT 64
#define NBLK ((NN + MT - 1) / MT)
#define LOG2E 1.4426950408889634f

typedef short bf16x8 __attribute__((ext_vector_type(8)));
typedef float f32x4 __attribute__((ext_vector_type(4)));
typedef unsigned short u16;
typedef unsigned int u32;

static __device__ __forceinline__ u16 f2bf(float f) {
  union { float f; u32 u; } v; v.f = f;
  u32 u = v.u + 0x7FFFu + ((v.u >> 16) & 1u);   // round-to-nearest-even
  return (u16)(u >> 16);
}
static __device__ __forceinline__ float rcp_(float x) {
  return __builtin_amdgcn_rcpf(x);
}
static __device__ __forceinline__ float ex2_(float x) {
  return __builtin_amdgcn_exp2f(x);
}
static __device__ __forceinline__ void gload_lds16(const void* g, void* l) {
  __builtin_amdgcn_global_load_lds(
      (const __attribute__((address_space(1))) void*)g,
      (__attribute__((address_space(3))) void*)l, 16, 0, 0);
}

// ---------------------------------------------------------------------------
// Prep: bf16-convert x, prepack MFMA B-fragments (8-wave layout), bias sums.
// Gate weights/biases are PRE-SCALED by log2e (gates i,f,o) / 2*log2e (gate g)
// so the device elementwise phase uses raw v_exp_f32 (exp2) directly.
// Gate-weight frag (w<8, g<4, kt<8, lane, j):
//   wpk[(((w*4+g)*8+kt)*64+lane)*8+j] = sc * W[col][k],
//   col = g*128 + w*16 + (lane&15),  k = kt*32 + (lane>>4)*8 + j,
//   W = [w_ih | w_hh] along K.
// ---------------------------------------------------------------------------
__global__ void k_prep(const float* __restrict__ x, u16* __restrict__ xb,
                       const float* __restrict__ wih1, const float* __restrict__ whh1, u16* __restrict__ wpk1,
                       const float* __restrict__ wih2, const float* __restrict__ whh2, u16* __restrict__ wpk2,
                       const float* __restrict__ lr1, const float* __restrict__ ll1, u16* __restrict__ epk1,
                       const float* __restrict__ lr2, const float* __restrict__ ll2, u16* __restrict__ epk2,
                       const float* __restrict__ linw, u16* __restrict__ hpk,
                       const float* __restrict__ bi1, const float* __restrict__ bh1, float* __restrict__ bs1,
                       const float* __restrict__ bi2, const float* __restrict__ bh2, float* __restrict__ bs2) {
  int b = blockIdx.x;
  if (b < 128) {
    const float* wih = (b < 64) ? wih1 : wih2;
    const float* whh = (b < 64) ? whh1 : whh2;
    u16* wpk = (b < 64) ? wpk1 : wpk2;
    int t = (b & 63) * 256 + threadIdx.x;          // 0..16383
    int lane = t & 63, kt = (t >> 6) & 7, g = (t >> 9) & 3, w = (t >> 11) & 7;
    int col = g * 128 + w * 16 + (lane & 15);
    int k0 = kt * 32 + (lane >> 4) * 8;
    float sc = (g == 2) ? 2.f * LOG2E : LOG2E;
#pragma unroll
    for (int j = 0; j < 8; ++j) {
      int k = k0 + j;
      float v = (k < 128) ? wih[col * 128 + k] : whh[col * 128 + k - 128];
      wpk[t * 8 + j] = f2bf(sc * v);
    }
  } else if (b < 160) {
    // epilogue weights: k<128 lin_r (over x), k>=128 lin_l (over h) — unscaled
    const float* lrw = (b < 144) ? lr1 : lr2;
    const float* llw = (b < 144) ? ll1 : ll2;
    u16* epk = (b < 144) ? epk1 : epk2;
    int t = ((b - 128) & 15) * 256 + threadIdx.x;  // 0..4095
    int lane = t & 63, kt = (t >> 6) & 7, w = (t >> 9) & 7;
    int col = w * 16 + (lane & 15);
    int k0 = kt * 32 + (lane >> 4) * 8;
#pragma unroll
    for (int j = 0; j < 8; ++j) {
      int k = k0 + j;
      epk[t * 8 + j] = f2bf(k < 128 ? lrw[col * 128 + k] : llw[col * 128 + k - 128]);
    }
  } else if (b < 164) {
    // head weights [64,128], waves 0..3 — unscaled
    int t = (b - 160) * 256 + threadIdx.x;         // 0..1023
    int lane = t & 63, kt = (t >> 6) & 3, w = (t >> 8) & 3;
    int col = w * 16 + (lane & 15);
    int k0 = kt * 32 + (lane >> 4) * 8;
#pragma unroll
    for (int j = 0; j < 8; ++j) hpk[t * 8 + j] = f2bf(linw[col * 128 + k0 + j]);
  } else if (b < 168) {
    int t = (b - 164) * 256 + threadIdx.x;         // 0..1023
    if (t < 1024) {
      int i = t & 511;
      float sc = ((i >> 7) == 2) ? 2.f * LOG2E : LOG2E;
      if (t < 512) bs1[i] = sc * (bi1[i] + bh1[i]);
      else bs2[i] = sc * (bi2[i] + bh2[i]);
    }
  } else {
    int i = (b - 168) * 256 + threadIdx.x;
    int stride = (gridDim.x - 168) * 256;
    for (; i < NN * 128 / 4; i += stride) {
      float4 v = ((const float4*)x)[i];
      ushort4 o;
      o.x = f2bf(v.x); o.y = f2bf(v.y); o.z = f2bf(v.z); o.w = f2bf(v.w);
      ((ushort4*)xb)[i] = o;
    }
  }
}

// ---------------------------------------------------------------------------
// Fused SAGE-LSTM layer, v3: 512 threads = 8 waves, MT=64 nodes, 1 block/CU.
// KEY CHANGE vs v2: the wave's full gate-weight B panel (32 bf16x8 = 128 VGPR)
// is loaded into REGISTERS once per block — zero global loads in the step loop
// except the x-gather (global_load_lds, latency hidden under h-MFMA+VALU).
// Gate biases folded into MFMA acc init. Sigmoid/tanh in exp2 domain
// (weights pre-scaled at prep).  LDS XOR-swizzle: byte ^= (row&15)<<4.
// ---------------------------------------------------------------------------
template <int L2>
__global__ __launch_bounds__(512, 2) void k_layer(
    const u16* __restrict__ xin, const int* __restrict__ src,
    const u16* __restrict__ wpk, const float* __restrict__ bsum,
    const u16* __restrict__ epk, const float* __restrict__ linlb,
    u16* __restrict__ hout, const u16* __restrict__ hpk,
    const float* __restrict__ linb, float* __restrict__ dout) {
  __shared__ __align__(16) u16 AX[2][MT * 128];   // 2 x 16 KB
  __shared__ __align__(16) u16 AH[2][MT * 128];   // 2 x 16 KB
  __shared__ int IDX[MT * DEG];                   // 4 KB

  const int tid = threadIdx.x;
  const int w = tid >> 6, l = tid & 63;
  const int lr = l & 15, lh = l >> 4;
  const int node0 = blockIdx.x * MT;

  // ---- hoisted weight panel: 32 frags = 128 VGPRs, loaded ONCE ----
  bf16x8 wreg[4][8];
#pragma unroll
  for (int g = 0; g < 4; ++g)
#pragma unroll
    for (int kt = 0; kt < 8; ++kt)
      wreg[g][kt] = *(const bf16x8*)(wpk + (size_t)(((w * 4 + g) * 8 + kt) * 64 + l) * 8);

  // neighbor indices (IDX[node][d]), contiguous in src
#pragma unroll
  for (int q = 0; q < 2; ++q) {
    int t = tid + q * 512;
    IDX[t] = (node0 + (t >> 4) < NN) ? src[node0 * DEG + t] : 0;
  }
  float gb[4];
#pragma unroll
  for (int g = 0; g < 4; ++g) gb[g] = bsum[g * 128 + w * 16 + lr];
  float eb = linlb[w * 16 + lr];
  __syncthreads();  // IDX ready

  // gather x_0 into AX[0]; wave w stages rows [8w, 8w+8)
#pragma unroll
  for (int p = 0; p < 2; ++p) {
    int row = w * 8 + p * 4 + lh;
    int idx = IDX[row * DEG];
    const char* gsw = (const char*)(xin + (size_t)idx * 128) +
                      ((lr * 16) ^ ((row & 15) << 4));
    gload_lds16(gsw, &AX[0][(w * 8 + p * 4) * 128]);
  }

  f32x4 c[4];
#pragma unroll
  for (int mt = 0; mt < 4; ++mt) c[mt] = (f32x4){0.f, 0.f, 0.f, 0.f};
  __syncthreads();  // x_0 gathered

#pragma unroll 1
  for (int step = 0; step < DEG; ++step) {
    const int cb = step & 1, nb = cb ^ 1;
    const u16* axc = AX[cb];
    const u16* ahc = AH[cb];

    // acc init = gate bias (pre-scaled): free bias add via MFMA C-in
    f32x4 acc[4][4];
#pragma unroll
    for (int mt = 0; mt < 4; ++mt)
#pragma unroll
      for (int g = 0; g < 4; ++g)
        acc[mt][g] = (f32x4){gb[g], gb[g], gb[g], gb[g]};

    // x-part of gates: K tiles 0..3 (B from registers)
#pragma unroll
    for (int kt = 0; kt < 4; ++kt) {
      bf16x8 af[4];
#pragma unroll
      for (int mt = 0; mt < 4; ++mt) {
        int row = mt * 16 + lr;
        af[mt] = *(const bf16x8*)((const char*)axc + row * 256 +
                                  ((kt * 64 + lh * 16) ^ ((row & 15) << 4)));
      }
#pragma unroll
      for (int g = 0; g < 4; ++g)
#pragma unroll
        for (int mt = 0; mt < 4; ++mt)
          acc[mt][g] = __builtin_amdgcn_mfma_f32_16x16x32_bf16(af[mt], wreg[g][kt], acc[mt][g], 0, 0, 0);
    }

    // issue next-step gather into AX[nb]; h-MFMA + elementwise cover latency
#pragma unroll
    for (int p = 0; p < 2; ++p) {
      int row = w * 8 + p * 4 + lh;
      int idx = (step < DEG - 1) ? IDX[row * DEG + step + 1]
                                 : ((node0 + row < NN) ? node0 + row : NN - 1);
      const char* gsw = (const char*)(xin + (size_t)idx * 128) +
                        ((lr * 16) ^ ((row & 15) << 4));
      gload_lds16(gsw, &AX[nb][(w * 8 + p * 4) * 128]);
    }

    // h-part of gates: K tiles 4..7 (h == 0 at step 0)
    if (step) {
#pragma unroll
      for (int kt = 0; kt < 4; ++kt) {
        bf16x8 af[4];
#pragma unroll
        for (int mt = 0; mt < 4; ++mt) {
          int row = mt * 16 + lr;
          af[mt] = *(const bf16x8*)((const char*)ahc + row * 256 +
                                    ((kt * 64 + lh * 16) ^ ((row & 15) << 4)));
        }
#pragma unroll
        for (int g = 0; g < 4; ++g)
#pragma unroll
          for (int mt = 0; mt < 4; ++mt)
            acc[mt][g] = __builtin_amdgcn_mfma_f32_16x16x32_bf16(af[mt], wreg[g][4 + kt], acc[mt][g], 0, 0, 0);
      }
    }

    // LSTM elementwise (exp2 domain); write new h (bf16) into AH[nb]
#pragma unroll
    for (int mt = 0; mt < 4; ++mt)
#pragma unroll
      for (int r = 0; r < 4; ++r) {
        float iv = rcp_(1.f + ex2_(-acc[mt][0][r]));
        float fv = rcp_(1.f + ex2_(-acc[mt][1][r]));
        float gv = 1.f - 2.f * rcp_(1.f + ex2_(acc[mt][2][r]));
        float ov = rcp_(1.f + ex2_(-acc[mt][3][r]));
        float cv = fv * c[mt][r] + iv * gv;
        c[mt][r] = cv;
        float th = 1.f - 2.f * rcp_(1.f + ex2_(2.f * LOG2E * cv));
        int row = mt * 16 + lh * 4 + r;
        int jj = 2 * (w * 16 + lr);
        *(u16*)((char*)AH[nb] + row * 256 + (jj ^ ((row & 15) << 4))) =
            f2bf(ov * th);
      }
    __syncthreads();
  }

  // Epilogue: out = lin_r(x_own) + lin_l(h_final) + b, ReLU.
  // AX[0] holds own input row (written at step 15), AH[0] the final h.
  f32x4 eacc[4];
#pragma unroll
  for (int mt = 0; mt < 4; ++mt) eacc[mt] = (f32x4){eb, eb, eb, eb};
#pragma unroll
  for (int kt = 0; kt < 8; ++kt) {
    const u16* srcb = (kt < 4) ? AX[0] : AH[0];
    int kb = (kt & 3) * 64 + lh * 16;
    bf16x8 af[4];
#pragma unroll
    for (int mt = 0; mt < 4; ++mt) {
      int row = mt * 16 + lr;
      af[mt] = *(const bf16x8*)((const char*)srcb + row * 256 +
                                (kb ^ ((row & 15) << 4)));
    }
    bf16x8 bf = *(const bf16x8*)(epk + (size_t)((w * 8 + kt) * 64 + l) * 8);
#pragma unroll
    for (int mt = 0; mt < 4; ++mt)
      eacc[mt] = __builtin_amdgcn_mfma_f32_16x16x32_bf16(af[mt], bf, eacc[mt], 0, 0, 0);
  }

  if constexpr (!L2) {
#pragma unroll
    for (int mt = 0; mt < 4; ++mt)
#pragma unroll
      for (int r = 0; r < 4; ++r) {
        int node = node0 + mt * 16 + lh * 4 + r;
        if (node < NN) {
          float v = fmaxf(eacc[mt][r], 0.f);
          hout[(size_t)node * 128 + w * 16 + lr] = f2bf(v);
        }
      }
  } else {
    // stash relu(h2) into AX[1], then fused 128->64 head (waves 0..3)
#pragma unroll
    for (int mt = 0; mt < 4; ++mt)
#pragma unroll
      for (int r = 0; r < 4; ++r) {
        int row = mt * 16 + lh * 4 + r;
        float v = fmaxf(eacc[mt][r], 0.f);
        int jj = 2 * (w * 16 + lr);
        *(u16*)((char*)AX[1] + row * 256 + (jj ^ ((row & 15) << 4))) = f2bf(v);
      }
    __syncthreads();
    if (w < 4) {
      float hb = linb[w * 16 + lr];
      f32x4 hacc[4];
#pragma unroll
      for (int mt = 0; mt < 4; ++mt) hacc[mt] = (f32x4){hb, hb, hb, hb};
#pragma unroll
      for (int kt = 0; kt < 4; ++kt) {
        bf16x8 af[4];
#pragma unroll
        for (int mt = 0; mt < 4; ++mt) {
          int row = mt * 16 + lr;
          af[mt] = *(const bf16x8*)((const char*)AX[1] + row * 256 +
                                    ((kt * 64 + lh * 16) ^ ((row & 15) << 4)));
        }
        bf16x8 bf = *(const bf16x8*)(hpk + (size_t)((w * 4 + kt) * 64 + l) * 8);
#pragma unroll
        for (int mt = 0; mt < 4; ++mt)
          hacc[mt] = __builtin_amdgcn_mfma_f32_16x16x32_bf16(af[mt], bf, hacc[mt], 0, 0, 0);
      }
#pragma unroll
      for (int mt = 0; mt < 4; ++mt)
#pragma unroll
        for (int r = 0; r < 4; ++r) {
          int node = node0 + mt * 16 + lh * 4 + r;
          if (node < NN) dout[(size_t)node * 64 + w * 16 + lr] = hacc[mt][r];
        }
    }
  }
}

extern "C" void kernel_launch(void* const* d_in, const int* in_sizes, int n_in,
                              void* d_out, int out_size, void* d_ws, size_t ws_size,
                              hipStream_t stream) {
  const float* x    = (const float*)d_in[0];
  const int*   edge = (const int*)d_in[1];   // src = first N*DEG entries
  const float* wih1 = (const float*)d_in[2];
  const float* whh1 = (const float*)d_in[3];
  const float* bih1 = (const float*)d_in[4];
  const float* bhh1 = (const float*)d_in[5];
  const float* ll1w = (const float*)d_in[6];
  const float* ll1b = (const float*)d_in[7];
  const float* lr1w = (const float*)d_in[8];
  const float* wih2 = (const float*)d_in[9];
  const float* whh2 = (const float*)d_in[10];
  const float* bih2 = (const float*)d_in[11];
  const float* bhh2 = (const float*)d_in[12];
  const float* ll2w = (const float*)d_in[13];
  const float* ll2b = (const float*)d_in[14];
  const float* lr2w = (const float*)d_in[15];
  const float* linw = (const float*)d_in[16];
  const float* linb = (const float*)d_in[17];

  char* ws = (char*)d_ws;
  u16* xb    = (u16*)(ws);                       // 12,800,000 B
  u16* h1b   = (u16*)(ws + 12800000);            // 12,800,000 B
  u16* wpk1  = (u16*)(ws + 25600000);            //    262,144 B
  u16* wpk2  = (u16*)(ws + 25862144);            //    262,144 B
  u16* epk1  = (u16*)(ws + 26124288);            //     65,536 B
  u16* epk2  = (u16*)(ws + 26189824);            //     65,536 B
  u16* hpk   = (u16*)(ws + 26255360);            //     16,384 B
  float* bs1 = (float*)(ws + 26271744);          //      2,048 B
  float* bs2 = (float*)(ws + 26273792);          //      2,048 B

  k_prep<<<1000, 256, 0, stream>>>(x, xb,
                                   wih1, whh1, wpk1, wih2, whh2, wpk2,
                                   lr1w, ll1w, epk1, lr2w, ll2w, epk2,
                                   linw, hpk,
                                   bih1, bhh1, bs1, bih2, bhh2, bs2);
  k_layer<0><<<NBLK, 512, 0, stream>>>(xb, edge, wpk1, bs1, epk1, ll1b,
                                       h1b, nullptr, nullptr, nullptr);
  k_layer<1><<<NBLK, 512, 0, stream>>>(h1b, edge, wpk2, bs2, epk2, ll2b,
                                       nullptr, hpk, linb, (float*)d_out);
}

// Round 4
// 583.894 us; speedup vs baseline: 4.2045x; 1.7729x over previous
//
#include <hip/hip_runtime.h>
#include <stdint.h>

#define NN 50000
#define DEG 16
#define MT 32
#define NBLK ((NN + MT - 1) / MT)
#define LOG2E 1.4426950408889634f

typedef short bf16x8 __attribute__((ext_vector_type(8)));
typedef float f32x4 __attribute__((ext_vector_type(4)));
typedef unsigned short u16;
typedef unsigned int u32;

static __device__ __forceinline__ u16 f2bf(float f) {
  union { float f; u32 u; } v; v.f = f;
  u32 u = v.u + 0x7FFFu + ((v.u >> 16) & 1u);   // round-to-nearest-even
  return (u16)(u >> 16);
}
static __device__ __forceinline__ float rcp_(float x) {
  return __builtin_amdgcn_rcpf(x);
}
static __device__ __forceinline__ float ex2_(float x) {
  return __builtin_amdgcn_exp2f(x);
}
static __device__ __forceinline__ void gload_lds16(const void* g, void* l) {
  __builtin_amdgcn_global_load_lds(
      (const __attribute__((address_space(1))) void*)g,
      (__attribute__((address_space(3))) void*)l, 16, 0, 0);
}

// ---------------------------------------------------------------------------
// Prep: bf16-convert x, prepack MFMA B-fragments (8-wave layout), bias sums.
// Gate weights/biases PRE-SCALED by log2e (i,f,o) / 2*log2e (g) so the
// elementwise phase uses raw v_exp_f32 (exp2) directly.
// Gate-weight frag (w<8, g<4, kt<8, lane, j):
//   wpk[(((w*4+g)*8+kt)*64+lane)*8+j] = sc * W[col][k],
//   col = g*128 + w*16 + (lane&15),  k = kt*32 + (lane>>4)*8 + j,
//   W = [w_ih | w_hh] along K.
// ---------------------------------------------------------------------------
__global__ void k_prep(const float* __restrict__ x, u16* __restrict__ xb,
                       const float* __restrict__ wih1, const float* __restrict__ whh1, u16* __restrict__ wpk1,
                       const float* __restrict__ wih2, const float* __restrict__ whh2, u16* __restrict__ wpk2,
                       const float* __restrict__ lr1, const float* __restrict__ ll1, u16* __restrict__ epk1,
                       const float* __restrict__ lr2, const float* __restrict__ ll2, u16* __restrict__ epk2,
                       const float* __restrict__ linw, u16* __restrict__ hpk,
                       const float* __restrict__ bi1, const float* __restrict__ bh1, float* __restrict__ bs1,
                       const float* __restrict__ bi2, const float* __restrict__ bh2, float* __restrict__ bs2) {
  int b = blockIdx.x;
  if (b < 128) {
    const float* wih = (b < 64) ? wih1 : wih2;
    const float* whh = (b < 64) ? whh1 : whh2;
    u16* wpk = (b < 64) ? wpk1 : wpk2;
    int t = (b & 63) * 256 + threadIdx.x;          // 0..16383
    int lane = t & 63, kt = (t >> 6) & 7, g = (t >> 9) & 3, w = (t >> 11) & 7;
    int col = g * 128 + w * 16 + (lane & 15);
    int k0 = kt * 32 + (lane >> 4) * 8;
    float sc = (g == 2) ? 2.f * LOG2E : LOG2E;
#pragma unroll
    for (int j = 0; j < 8; ++j) {
      int k = k0 + j;
      float v = (k < 128) ? wih[col * 128 + k] : whh[col * 128 + k - 128];
      wpk[t * 8 + j] = f2bf(sc * v);
    }
  } else if (b < 160) {
    // epilogue weights: k<128 lin_r (over x), k>=128 lin_l (over h) — unscaled
    const float* lrw = (b < 144) ? lr1 : lr2;
    const float* llw = (b < 144) ? ll1 : ll2;
    u16* epk = (b < 144) ? epk1 : epk2;
    int t = ((b - 128) & 15) * 256 + threadIdx.x;  // 0..4095
    int lane = t & 63, kt = (t >> 6) & 7, w = (t >> 9) & 7;
    int col = w * 16 + (lane & 15);
    int k0 = kt * 32 + (lane >> 4) * 8;
#pragma unroll
    for (int j = 0; j < 8; ++j) {
      int k = k0 + j;
      epk[t * 8 + j] = f2bf(k < 128 ? lrw[col * 128 + k] : llw[col * 128 + k - 128]);
    }
  } else if (b < 164) {
    // head weights [64,128], waves 0..3 — unscaled
    int t = (b - 160) * 256 + threadIdx.x;         // 0..1023
    int lane = t & 63, kt = (t >> 6) & 3, w = (t >> 8) & 3;
    int col = w * 16 + (lane & 15);
    int k0 = kt * 32 + (lane >> 4) * 8;
#pragma unroll
    for (int j = 0; j < 8; ++j) hpk[t * 8 + j] = f2bf(linw[col * 128 + k0 + j]);
  } else if (b < 168) {
    int t = (b - 164) * 256 + threadIdx.x;         // 0..1023
    if (t < 1024) {
      int i = t & 511;
      float sc = ((i >> 7) == 2) ? 2.f * LOG2E : LOG2E;
      if (t < 512) bs1[i] = sc * (bi1[i] + bh1[i]);
      else bs2[i] = sc * (bi2[i] + bh2[i]);
    }
  } else {
    int i = (b - 168) * 256 + threadIdx.x;
    int stride = (gridDim.x - 168) * 256;
    for (; i < NN * 128 / 4; i += stride) {
      float4 v = ((const float4*)x)[i];
      ushort4 o;
      o.x = f2bf(v.x); o.y = f2bf(v.y); o.z = f2bf(v.z); o.w = f2bf(v.w);
      ((ushort4*)xb)[i] = o;
    }
  }
}

// ---------------------------------------------------------------------------
// Fused SAGE-LSTM layer, v4: 512 threads = 8 waves, MT=32 nodes/block.
// KEY CHANGE vs v3: node tile halved so the register budget ACTUALLY fits
// 256 regs/wave (wreg 128 + acc 32 + c 8 + temps ~40) -> no scratch spills
// (v3 spilled wreg: WRITE_SIZE 120MB vs 13MB output).
// Wave w owns gate cols [16w,16w+16) of each gate; weight panel register-
// resident for the whole block. One global_load_lds gather per wave per
// step, issued at the TOP of the step (full step covers random-L3 latency).
// LDS XOR-swizzle: byte ^= (row&15)<<4.
// ---------------------------------------------------------------------------
template <int L2>
__global__ __launch_bounds__(512, 2) void k_layer(
    const u16* __restrict__ xin, const int* __restrict__ src,
    const u16* __restrict__ wpk, const float* __restrict__ bsum,
    const u16* __restrict__ epk, const float* __restrict__ linlb,
    u16* __restrict__ hout, const u16* __restrict__ hpk,
    const float* __restrict__ linb, float* __restrict__ dout) {
  __shared__ __align__(16) u16 AX[2][MT * 128];   // 2 x 8 KB
  __shared__ __align__(16) u16 AH[2][MT * 128];   // 2 x 8 KB
  __shared__ int IDX[MT * DEG];                   // 2 KB

  const int tid = threadIdx.x;
  const int w = tid >> 6, l = tid & 63;
  const int lr = l & 15, lh = l >> 4;
  const int node0 = blockIdx.x * MT;

  // ---- register-resident weight panel: 32 frags = 128 VGPRs, loaded ONCE ----
  bf16x8 wreg[4][8];
#pragma unroll
  for (int g = 0; g < 4; ++g)
#pragma unroll
    for (int kt = 0; kt < 8; ++kt)
      wreg[g][kt] = *(const bf16x8*)(wpk + (size_t)(((w * 4 + g) * 8 + kt) * 64 + l) * 8);

  // neighbor indices (IDX[node][d]), contiguous in src; one per thread
  IDX[tid] = (node0 + (tid >> 4) < NN) ? src[node0 * DEG + tid] : 0;

  float gb[4];
#pragma unroll
  for (int g = 0; g < 4; ++g) gb[g] = bsum[g * 128 + w * 16 + lr];
  float eb = linlb[w * 16 + lr];
  __syncthreads();  // IDX ready

  // gather x_0 into AX[0]; wave w stages rows [4w, 4w+4) (one instruction)
  const int grow = w * 4 + lh;  // this lane's gather row
  {
    int idx = IDX[grow * DEG];
    const char* gsw = (const char*)(xin + (size_t)idx * 128) +
                      ((lr * 16) ^ ((grow & 15) << 4));
    gload_lds16(gsw, &AX[0][(w * 4) * 128]);
  }

  f32x4 c[2];
  c[0] = (f32x4){0.f, 0.f, 0.f, 0.f};
  c[1] = (f32x4){0.f, 0.f, 0.f, 0.f};
  __syncthreads();  // x_0 gathered

#pragma unroll 1
  for (int step = 0; step < DEG; ++step) {
    const int cb = step & 1, nb = cb ^ 1;
    const u16* axc = AX[cb];
    const u16* ahc = AH[cb];

    // issue next-step gather into AX[nb] FIRST: AX[nb] is free (its readers
    // finished before the previous barrier); whole step hides the latency.
    {
      int idx = (step < DEG - 1) ? IDX[grow * DEG + step + 1]
                                 : ((node0 + grow < NN) ? node0 + grow : NN - 1);
      const char* gsw = (const char*)(xin + (size_t)idx * 128) +
                        ((lr * 16) ^ ((grow & 15) << 4));
      gload_lds16(gsw, &AX[nb][(w * 4) * 128]);
    }

    // acc init = gate bias (pre-scaled): free bias add via MFMA C-in
    f32x4 acc[2][4];
#pragma unroll
    for (int mt = 0; mt < 2; ++mt)
#pragma unroll
      for (int g = 0; g < 4; ++g)
        acc[mt][g] = (f32x4){gb[g], gb[g], gb[g], gb[g]};

    // x-part of gates: K tiles 0..3 (B from registers)
#pragma unroll
    for (int kt = 0; kt < 4; ++kt) {
      bf16x8 af[2];
#pragma unroll
      for (int mt = 0; mt < 2; ++mt) {
        int row = mt * 16 + lr;
        af[mt] = *(const bf16x8*)((const char*)axc + row * 256 +
                                  ((kt * 64 + lh * 16) ^ ((row & 15) << 4)));
      }
#pragma unroll
      for (int g = 0; g < 4; ++g)
#pragma unroll
        for (int mt = 0; mt < 2; ++mt)
          acc[mt][g] = __builtin_amdgcn_mfma_f32_16x16x32_bf16(af[mt], wreg[g][kt], acc[mt][g], 0, 0, 0);
    }

    // h-part of gates: K tiles 4..7 (h == 0 at step 0)
    if (step) {
#pragma unroll
      for (int kt = 0; kt < 4; ++kt) {
        bf16x8 af[2];
#pragma unroll
        for (int mt = 0; mt < 2; ++mt) {
          int row = mt * 16 + lr;
          af[mt] = *(const bf16x8*)((const char*)ahc + row * 256 +
                                    ((kt * 64 + lh * 16) ^ ((row & 15) << 4)));
        }
#pragma unroll
        for (int g = 0; g < 4; ++g)
#pragma unroll
          for (int mt = 0; mt < 2; ++mt)
            acc[mt][g] = __builtin_amdgcn_mfma_f32_16x16x32_bf16(af[mt], wreg[g][4 + kt], acc[mt][g], 0, 0, 0);
      }
    }

    // LSTM elementwise (exp2 domain); write new h (bf16) into AH[nb]
#pragma unroll
    for (int mt = 0; mt < 2; ++mt)
#pragma unroll
      for (int r = 0; r < 4; ++r) {
        float iv = rcp_(1.f + ex2_(-acc[mt][0][r]));
        float fv = rcp_(1.f + ex2_(-acc[mt][1][r]));
        float gv = 1.f - 2.f * rcp_(1.f + ex2_(acc[mt][2][r]));
        float ov = rcp_(1.f + ex2_(-acc[mt][3][r]));
        float cv = fv * c[mt][r] + iv * gv;
        c[mt][r] = cv;
        float th = 1.f - 2.f * rcp_(1.f + ex2_(2.f * LOG2E * cv));
        int row = mt * 16 + lh * 4 + r;
        int jj = 2 * (w * 16 + lr);
        *(u16*)((char*)AH[nb] + row * 256 + (jj ^ ((row & 15) << 4))) =
            f2bf(ov * th);
      }
    __syncthreads();
  }

  // Epilogue: out = lin_r(x_own) + lin_l(h_final) + b, ReLU.
  // AX[0] holds own input row (written at step 15), AH[0] the final h.
  f32x4 eacc[2];
  eacc[0] = (f32x4){eb, eb, eb, eb};
  eacc[1] = (f32x4){eb, eb, eb, eb};
#pragma unroll
  for (int kt = 0; kt < 8; ++kt) {
    const u16* srcb = (kt < 4) ? AX[0] : AH[0];
    int kb = (kt & 3) * 64 + lh * 16;
    bf16x8 af[2];
#pragma unroll
    for (int mt = 0; mt < 2; ++mt) {
      int row = mt * 16 + lr;
      af[mt] = *(const bf16x8*)((const char*)srcb + row * 256 +
                                (kb ^ ((row & 15) << 4)));
    }
    bf16x8 bf = *(const bf16x8*)(epk + (size_t)((w * 8 + kt) * 64 + l) * 8);
#pragma unroll
    for (int mt = 0; mt < 2; ++mt)
      eacc[mt] = __builtin_amdgcn_mfma_f32_16x16x32_bf16(af[mt], bf, eacc[mt], 0, 0, 0);
  }

  if constexpr (!L2) {
#pragma unroll
    for (int mt = 0; mt < 2; ++mt)
#pragma unroll
      for (int r = 0; r < 4; ++r) {
        int node = node0 + mt * 16 + lh * 4 + r;
        if (node < NN) {
          float v = fmaxf(eacc[mt][r], 0.f);
          hout[(size_t)node * 128 + w * 16 + lr] = f2bf(v);
        }
      }
  } else {
    // stash relu(h2) into AX[1], then fused 128->64 head (waves 0..3)
#pragma unroll
    for (int mt = 0; mt < 2; ++mt)
#pragma unroll
      for (int r = 0; r < 4; ++r) {
        int row = mt * 16 + lh * 4 + r;
        float v = fmaxf(eacc[mt][r], 0.f);
        int jj = 2 * (w * 16 + lr);
        *(u16*)((char*)AX[1] + row * 256 + (jj ^ ((row & 15) << 4))) = f2bf(v);
      }
    __syncthreads();
    if (w < 4) {
      float hb = linb[w * 16 + lr];
      f32x4 hacc[2];
      hacc[0] = (f32x4){hb, hb, hb, hb};
      hacc[1] = (f32x4){hb, hb, hb, hb};
#pragma unroll
      for (int kt = 0; kt < 4; ++kt) {
        bf16x8 af[2];
#pragma unroll
        for (int mt = 0; mt < 2; ++mt) {
          int row = mt * 16 + lr;
          af[mt] = *(const bf16x8*)((const char*)AX[1] + row * 256 +
                                    ((kt * 64 + lh * 16) ^ ((row & 15) << 4)));
        }
        bf16x8 bf = *(const bf16x8*)(hpk + (size_t)((w * 4 + kt) * 64 + l) * 8);
#pragma unroll
        for (int mt = 0; mt < 2; ++mt)
          hacc[mt] = __builtin_amdgcn_mfma_f32_16x16x32_bf16(af[mt], bf, hacc[mt], 0, 0, 0);
      }
#pragma unroll
      for (int mt = 0; mt < 2; ++mt)
#pragma unroll
        for (int r = 0; r < 4; ++r) {
          int node = node0 + mt * 16 + lh * 4 + r;
          if (node < NN) dout[(size_t)node * 64 + w * 16 + lr] = hacc[mt][r];
        }
    }
  }
}

extern "C" void kernel_launch(void* const* d_in, const int* in_sizes, int n_in,
                              void* d_out, int out_size, void* d_ws, size_t ws_size,
                              hipStream_t stream) {
  const float* x    = (const float*)d_in[0];
  const int*   edge = (const int*)d_in[1];   // src = first N*DEG entries
  const float* wih1 = (const float*)d_in[2];
  const float* whh1 = (const float*)d_in[3];
  const float* bih1 = (const float*)d_in[4];
  const float* bhh1 = (const float*)d_in[5];
  const float* ll1w = (const float*)d_in[6];
  const float* ll1b = (const float*)d_in[7];
  const float* lr1w = (const float*)d_in[8];
  const float* wih2 = (const float*)d_in[9];
  const float* whh2 = (const float*)d_in[10];
  const float* bih2 = (const float*)d_in[11];
  const float* bhh2 = (const float*)d_in[12];
  const float* ll2w = (const float*)d_in[13];
  const float* ll2b = (const float*)d_in[14];
  const float* lr2w = (const float*)d_in[15];
  const float* linw = (const float*)d_in[16];
  const float* linb = (const float*)d_in[17];

  char* ws = (char*)d_ws;
  u16* xb    = (u16*)(ws);                       // 12,800,000 B
  u16* h1b   = (u16*)(ws + 12800000);            // 12,800,000 B
  u16* wpk1  = (u16*)(ws + 25600000);            //    262,144 B
  u16* wpk2  = (u16*)(ws + 25862144);            //    262,144 B
  u16* epk1  = (u16*)(ws + 26124288);            //     65,536 B
  u16* epk2  = (u16*)(ws + 26189824);            //     65,536 B
  u16* hpk   = (u16*)(ws + 26255360);            //     16,384 B
  float* bs1 = (float*)(ws + 26271744);          //      2,048 B
  float* bs2 = (float*)(ws + 26273792);          //      2,048 B

  k_prep<<<1000, 256, 0, stream>>>(x, xb,
                                   wih1, whh1, wpk1, wih2, whh2, wpk2,
                                   lr1w, ll1w, epk1, lr2w, ll2w, epk2,
                                   linw, hpk,
                                   bih1, bhh1, bs1, bih2, bhh2, bs2);
  k_layer<0><<<NBLK, 512, 0, stream>>>(xb, edge, wpk1, bs1, epk1, ll1b,
                                       h1b, nullptr, nullptr, nullptr);
  k_layer<1><<<NBLK, 512, 0, stream>>>(h1b, edge, wpk2, bs2, epk2, ll2b,
                                       nullptr, hpk, linb, (float*)d_out);
}